// Round 16
// baseline (62.899 us; speedup 1.0000x reference)
//
#include <hip/hip_runtime.h>

#define W     768
#define PIX   (768*768)
#define NMAPS 16            // 0..7 anno, 8..15 pred-argmax
#define TROWS 6
#define TPX   (TROWS*W)     // 4608 px per tile
#define NT    (768/TROWS)   // 128 tiles per map
#define NB    (NT-1)        // 127 tile boundaries per map
#define SW    128           // strip width in px (2 px/lane), 6 strips = 6 waves
#define CSLOT 16            // ints per counter slot (64 B line)

// Labels are PACKED everywhere: (label<<2) | cls. Within a component all
// pixels share cls, and min over packed == min over label -> cls bits are
// invariant under atomicMin unions.

__device__ __forceinline__ int find_root_p(volatile int* L, int x) {
    int y = L[x] >> 2;
    while (y != x) { x = y; y = L[x] >> 2; }
    return x;
}

// Unite; true iff a link event occurred (two roots merged). Parents only
// decrease -> acyclic; each index loses rootness at most once, so
// #link events == #merges exactly, independent of atomic ordering.
__device__ __forceinline__ bool unite_p(int* L, int a, int b, int c) {
    volatile int* Lv = L;
    while (true) {
        a = find_root_p(Lv, a);
        b = find_root_p(Lv, b);
        if (a == b) return false;
        if (a > b) { int t = a; a = b; b = t; }
        int old = atomicMin(&L[b], (a << 2) | c);
        if ((old >> 2) == b) return true;
        b = old >> 2;
    }
}

// ---------------- kernels ----------------

// One block per (map, 6-row tile), 384 threads = 6 waves. Wave wid owns the
// 128-px strip [wid*128, wid*128+128) of EVERY row (2 px/lane, float2/int2
// loads) -> 6 iterations per wave (was 18), vertical neighbors same-wave
// with a single prev-row register slot. Run-break masks for the 128-px
// strip row come from 4 class-bit ballots via bit algebra:
//   d0 bit l = (c0[l] != c1[l-1]) | (l==0)   [run starts at even pos 2l]
//   d1 bit l = (c1[l] != c0[l])              [run starts at odd pos 2l+1]
// Counting is runs - links (popcounts of d-masks; unions decrement).
// Phase 3 touches only tile-boundary rows 0 and 5 (compressed labels +
// boundary-reachable root self-pointers).
__global__ __launch_bounds__(384) void fused_k(const float* __restrict__ pred,
                                               const int*   __restrict__ anno,
                                               int* __restrict__ labels,
                                               int* __restrict__ counts, int m0) {
    __shared__ int lab[TPX];               // 18 KB packed (label<<2)|cls
    __shared__ int s2[6], s3[6];

    int mc   = blockIdx.x / NT;
    int t    = blockIdx.x - mc * NT;
    int m    = m0 + mc;
    int tid  = threadIdx.x;
    int wid  = tid >> 6;                   // strip 0..5
    int lane = tid & 63;

    unsigned long long lem = (lane == 63) ? ~0ULL : ((2ULL << lane) - 1);
    unsigned long long ltm = lem ^ (1ULL << lane);

    int pc0 = 0, pc1 = 0;                  // prev-row classes (this lane's 2 px)
    int pr0 = 0, pr1 = 0;                  // prev-row run-start positions (strip-local)
    int c2 = 0, c3 = 0;                    // runs - links accumulators

    const int*   asrc = anno + (size_t)m * PIX + (size_t)t * TPX;
    const float* psrc = pred + (size_t)(m < 8 ? 0 : (m - 8)) * 4 * PIX + (size_t)t * TPX;
    bool is_anno = (m < 8);

    int sp = wid * SW + 2 * lane;          // strip-local px0 column offset in row

    // ---- prefetch row 0 ----
    int2   na = make_int2(0, 0);
    float2 nv0 = {0,0}, nv1 = {0,0}, nv2 = {0,0}, nv3 = {0,0};
    if (is_anno) {
        na = *(const int2*)&asrc[sp];
    } else {
        const float2* f = (const float2*)psrc;
        int i2 = sp >> 1;
        nv0 = f[i2];
        nv1 = f[(PIX >> 1) + i2];
        nv2 = f[2 * (PIX >> 1) + i2];
        nv3 = f[3 * (PIX >> 1) + i2];
    }

    // ---- phase A: 6 rows, decode 2 px/lane, run-starts, vertical unions ----
    #pragma unroll
    for (int r = 0; r < TROWS; ++r) {
        int tb  = r * W + wid * SW;        // tile-local strip base this row
        int px0 = tb + 2 * lane;
        int2   ca = na;
        float2 v0 = nv0, v1 = nv1, v2 = nv2, v3 = nv3;
        if (r + 1 < TROWS) {               // prefetch next row
            int spn = px0 + W;
            if (is_anno) {
                na = *(const int2*)&asrc[spn];
            } else {
                const float2* f = (const float2*)psrc;
                int i2 = spn >> 1;
                nv0 = f[i2];
                nv1 = f[(PIX >> 1) + i2];
                nv2 = f[2 * (PIX >> 1) + i2];
                nv3 = f[3 * (PIX >> 1) + i2];
            }
        }
        int c0, c1;
        if (is_anno) {
            c0 = ca.x & 3; c1 = ca.y & 3;
        } else {
            // strict '>' = first-max (jnp.argmax)
            {   float bv = v0.x; c0 = 0;
                if (v1.x > bv) { bv = v1.x; c0 = 1; }
                if (v2.x > bv) { bv = v2.x; c0 = 2; }
                if (v3.x > bv) { bv = v3.x; c0 = 3; } }
            {   float bv = v0.y; c1 = 0;
                if (v1.y > bv) { bv = v1.y; c1 = 1; }
                if (v2.y > bv) { bv = v2.y; c1 = 2; }
                if (v3.y > bv) { bv = v3.y; c1 = 3; } }
        }
        unsigned long long blo0 = __ballot(c0 & 1);
        unsigned long long bhi0 = __ballot(c0 & 2);
        unsigned long long blo1 = __ballot(c1 & 1);
        unsigned long long bhi1 = __ballot(c1 & 2);
        unsigned long long d0 = ((blo0 ^ (blo1 << 1)) | (bhi0 ^ (bhi1 << 1))) | 1ULL;
        unsigned long long d1 = (blo1 ^ blo0) | (bhi1 ^ bhi0);
        if (lane == 0) {                   // run counts per class (both planes)
            c2 += (int)__popcll(d0 & bhi0 & ~blo0) + (int)__popcll(d1 & bhi1 & ~blo1);
            c3 += (int)__popcll(d0 & bhi0 &  blo0) + (int)__popcll(d1 & bhi1 &  blo1);
        }
        int rs0 = 2 * (63 - __clzll(d0 & lem));          // d0 bit0 always set
        unsigned long long mm = d1 & ltm;
        if (mm) { int q = 2 * (63 - __clzll(mm)) + 1; if (q > rs0) rs0 = q; }
        int rs1 = ((d1 >> lane) & 1) ? 2 * lane + 1 : rs0;
        *(int2*)&lab[px0] = make_int2(((tb + rs0) << 2) | c0,
                                      ((tb + rs1) << 2) | c1);
        if (r > 0) {                       // vertical per-run-pair unions (same wave)
            if ((c0 & 2) && c0 == pc0) {
                int mx = rs0 > pr0 ? rs0 : pr0;
                if (mx == 2 * lane && unite_p(lab, px0 - W, px0, c0)) {
                    if (c0 == 2) c2--; else c3--;
                }
            }
            if ((c1 & 2) && c1 == pc1) {
                int mx = rs1 > pr1 ? rs1 : pr1;
                if (mx == 2 * lane + 1 && unite_p(lab, px0 + 1 - W, px0 + 1, c1)) {
                    if (c1 == 2) c2--; else c3--;
                }
            }
        }
        pc0 = c0; pc1 = c1; pr0 = rs0; pr1 = rs1;
    }
    __syncthreads();

    // ---- stitch phase: 30 cross-strip horizontal joins ----
    if (tid < TROWS * 5) {
        int row = tid / 5, s = tid % 5 + 1;
        int px  = row * W + s * SW;
        int v = lab[px], c = v & 3;
        if (c & 2) {
            int vl = lab[px - 1];
            if ((vl & 3) == c && unite_p(lab, px - 1, px, c)) {
                if (c == 2) c2--; else c3--;
            }
        }
    }
    __syncthreads();

    // ---- phase 3: boundary rows 0 and TROWS-1 only ----
    int lbase = t * TPX;                   // map-local base of this tile
    int* gl = labels + (size_t)mc * PIX + lbase;
    #pragma unroll
    for (int q = 0; q < 2; ++q) {
        int r   = q ? (TROWS - 1) : 0;
        int px0 = r * W + wid * SW + 2 * lane;
        int v0 = lab[px0], v1 = lab[px0 + 1];
        int c0 = v0 & 3, c1 = v1 & 3;
        int r0 = (c0 & 2) ? find_root_p(lab, px0)     : px0;
        int r1 = (c1 & 2) ? find_root_p(lab, px0 + 1) : px0 + 1;
        *(int2*)&gl[px0] = make_int2(((lbase + r0) << 2) | c0,
                                     ((lbase + r1) << 2) | c1);
        int rl = __shfl_up(r1, 1);         // prev lane's second root
        if ((c0 & 2) && (lane == 0 || rl != r0))
            gl[r0] = ((lbase + r0) << 2) | c0;   // root self-pointer (idempotent)
        if ((c1 & 2) && r1 != r0)
            gl[r1] = ((lbase + r1) << 2) | c1;
    }
    // reduce (runs - links) -> one padded atomic per (block, class)
    for (int off = 32; off; off >>= 1) {
        c2 += __shfl_down(c2, off, 64);
        c3 += __shfl_down(c3, off, 64);
    }
    if (lane == 0) { s2[wid] = c2; s3[wid] = c3; }
    __syncthreads();
    if (tid == 0) {
        int t2 = s2[0] + s2[1] + s2[2] + s2[3] + s2[4] + s2[5];
        int t3 = s3[0] + s3[1] + s3[2] + s3[3] + s3[4] + s3[5];
        if (t2) atomicAdd(&counts[(m * 2 + 0) * CSLOT], t2);
        if (t3) atomicAdd(&counts[(m * 2 + 1) * CSLOT], t3);
    }
}

// Cross-tile boundary edges on packed labels, 2 columns per thread (int2).
// Run-dedup via shfl; duplicate unions are idempotent and count only real
// merges. blockIdx.y = map -> counts index is block-uniform.
__global__ __launch_bounds__(256) void boundary_k(int* __restrict__ labels,
                                                  int* __restrict__ counts, int m0) {
    __shared__ int s2[4], s3[4];
    const int HM = NB * (W / 2);               // 48768 col-pairs per map
    int i    = blockIdx.x * 256 + threadIdx.x;
    int mc   = blockIdx.y;
    int m    = m0 + mc;
    int lane = threadIdx.x & 63;

    int m2 = 0, m3 = 0;
    if (i < HM) {
        int b   = i / (W / 2);
        int col = (i - b * (W / 2)) * 2;
        int* L  = labels + (size_t)mc * PIX;
        int p1  = b * TPX + (TROWS - 1) * W + col;   // tile b, last row
        int p2  = p1 + W;                            // tile b+1, row 0
        int2 va = *(const int2*)&L[p1];
        int2 vb = *(const int2*)&L[p2];
        int pay = __shfl_up(va.y, 1), pby = __shfl_up(vb.y, 1);
        int c0 = va.x & 3;
        if (c0 == (vb.x & 3) && (c0 & 2)) {
            bool red = (lane > 0) && (pay == va.x) && (pby == vb.x);
            if (!red && unite_p(L, p1, p2, c0)) { if (c0 == 2) m2++; else m3++; }
        }
        int c1 = va.y & 3;
        if (c1 == (vb.y & 3) && (c1 & 2)) {
            bool red = (va.x == va.y) && (vb.x == vb.y);
            if (!red && unite_p(L, p1 + 1, p2 + 1, c1)) { if (c1 == 2) m2++; else m3++; }
        }
    }
    for (int off = 32; off; off >>= 1) {
        m2 += __shfl_down(m2, off, 64);
        m3 += __shfl_down(m3, off, 64);
    }
    int wid = threadIdx.x >> 6;
    if (lane == 0) { s2[wid] = m2; s3[wid] = m3; }
    __syncthreads();
    if (threadIdx.x == 0) {
        int t2 = s2[0] + s2[1] + s2[2] + s2[3];
        int t3 = s3[0] + s3[1] + s3[2] + s3[3];
        if (t2) atomicSub(&counts[(m * 2 + 0) * CSLOT], t2);
        if (t3) atomicSub(&counts[(m * 2 + 1) * CSLOT], t3);
    }
}

__global__ void final_k(const int* __restrict__ counts, float* __restrict__ out) {
    float s = 0.0f;
    for (int b = 0; b < 8; ++b) {
        float a2 = (float)counts[(b * 2 + 0) * CSLOT];
        float a3 = (float)counts[(b * 2 + 1) * CSLOT];
        float p2 = (float)counts[((8 + b) * 2 + 0) * CSLOT];
        float p3 = (float)counts[((8 + b) * 2 + 1) * CSLOT];
        float t2 = 1.0f - 2.0f * fminf(p2, a2) / (a2 + p2);
        float t3 = 1.0f - 2.0f * fminf(p3, a3) / (a3 + p3);
        s += t2 + t3;
    }
    out[0] = 0.5f * s;
}

// ---------------- launch ----------------

extern "C" void kernel_launch(void* const* d_in, const int* in_sizes, int n_in,
                              void* d_out, int out_size, void* d_ws, size_t ws_size,
                              hipStream_t stream) {
    const float* pred = (const float*)d_in[0];   // (8,4,1,768,768) f32
    const int*   anno = (const int*)d_in[1];     // (8,1,768,768) i32
    float* out = (float*)d_out;

    int* counts = (int*)d_ws;                    // 32*CSLOT ints = 2 KB
    char* base  = (char*)d_ws + 4096;

    const size_t per_map = (size_t)PIX * 4;      // packed labels only
    size_t avail = (ws_size > 4096) ? ws_size - 4096 : 0;
    int K = (int)(avail / per_map);
    if (K > NMAPS) K = NMAPS;
    if (K < 1)     K = 1;    // best effort; needs ~2.4 MB min

    hipMemsetAsync(counts, 0, 32 * CSLOT * sizeof(int), stream);

    const int HM = NB * (W / 2);                 // 48768 col-pairs per map
    for (int m0 = 0; m0 < NMAPS; m0 += K) {
        int nm = NMAPS - m0; if (nm > K) nm = K;
        int* labels = (int*)base;
        fused_k   <<<dim3(nm * NT), 384, 0, stream>>>(pred, anno, labels, counts, m0);
        boundary_k<<<dim3((HM + 255) / 256, nm), 256, 0, stream>>>(labels, counts, m0);
    }
    final_k<<<1, 1, 0, stream>>>(counts, out);
}